// Round 3
// baseline (3161.208 us; speedup 1.0000x reference)
//
#include <hip/hip_runtime.h>
#include <math.h>

#define DIM 128
#define HEADS 4
#define EPS 1e-5f
#define NBLK 1024

// ---------- dtype-flex helpers ----------
__device__ __forceinline__ float us2f(unsigned short u) {
  union { unsigned int i; float f; } c; c.i = ((unsigned int)u) << 16; return c.f;
}
__device__ __forceinline__ unsigned short f2us(float f) {
  union { float ff; unsigned int i; } c; c.ff = f;
  return (unsigned short)((c.i + 0x7FFFu + ((c.i >> 16) & 1u)) >> 16);
}
// fl32: 1 -> buffers hold float32, 0 -> bfloat16
__device__ __forceinline__ float ldf(const void* p, size_t i, int fl32) {
  return fl32 ? ((const float*)p)[i] : us2f(((const unsigned short*)p)[i]);
}
__device__ __forceinline__ float4 ldf4(const void* p, size_t i, int fl32) {
  if (fl32) return *(const float4*)((const float*)p + i);
  ushort4 u = *(const ushort4*)((const unsigned short*)p + i);
  return make_float4(us2f(u.x), us2f(u.y), us2f(u.z), us2f(u.w));
}
__device__ __forceinline__ float gelu_exact(float v) {
  return 0.5f * v * (1.0f + erff(v * 0.7071067811865475f));
}
__device__ __forceinline__ void atomicMaxFloatCAS(float* addr, float val) {
  int* ai = (int*)addr;
  int old = *(volatile int*)ai;
  while (__int_as_float(old) < val) {
    int assumed = old;
    old = atomicCAS(ai, assumed, __float_as_int(val));
    if (old == assumed) break;
  }
}

// ---------- dtype detection: bf16-view of N(0,1) data has 0 insane values;
// ---------- f32 data misread as bf16 has ~30% insane. ----------
__global__ void __launch_bounds__(256)
k_detect(const unsigned short* __restrict__ x, long n, int* __restrict__ dflag) {
  long lim = n < 8192 ? n : 8192;
  int bad = 0;
  for (long i = threadIdx.x; i < lim; i += 256) {
    float v = us2f(x[i]);
    float a = fabsf(v);
    if (!(a == 0.0f || (a > 1e-30f && a < 1e3f))) bad++;  // NaN/inf/huge/denormal
  }
  __shared__ int sb[256];
  sb[threadIdx.x] = bad;
  __syncthreads();
  for (int off = 128; off > 0; off >>= 1) {
    if ((int)threadIdx.x < off) sb[threadIdx.x] += sb[threadIdx.x + off];
    __syncthreads();
  }
  if (threadIdx.x == 0) dflag[0] = (sb[0] > 32) ? 1 : 0;
}

// ---------- kernels ----------
__global__ void k_init_minf(float* __restrict__ m, int n) {
  int i = blockIdx.x * blockDim.x + threadIdx.x;
  if (i < n) m[i] = -INFINITY;
}

__global__ void k_deg(const int* __restrict__ dst, const void* __restrict__ ew,
                      float* __restrict__ deg, int E, const int* __restrict__ df) {
  const int fl32 = *df;
  int e = blockIdx.x * blockDim.x + threadIdx.x;
  if (e < E) {
    float w = ldf(ew, e, fl32);
    if (isfinite(w)) atomicAdd(&deg[dst[e]], w);
  }
}

__global__ void k_dis(float* __restrict__ deg, int N) {
  int i = blockIdx.x * blockDim.x + threadIdx.x;
  if (i < N) {
    float d = deg[i];
    deg[i] = (d > 0.0f) ? rsqrtf(fmaxf(d, 1e-30f)) : 0.0f;
  }
}

__global__ void __launch_bounds__(128)
k_gemm_dual(const void* __restrict__ x, const void* __restrict__ Wg,
            const void* __restrict__ Wl, const void* __restrict__ bl,
            unsigned short* __restrict__ xw, unsigned short* __restrict__ xl, int N,
            const int* __restrict__ df) {
  const int fl32 = *df;
  const int R = 8;
  __shared__ float xs[R][DIM];
  int c = threadIdx.x;
  int r0 = blockIdx.x * R;
  for (int r = 0; r < R; ++r) {
    int row = r0 + r;
    xs[r][c] = (row < N) ? ldf(x, (size_t)row * DIM + c, fl32) : 0.0f;
  }
  __syncthreads();
  float accg[R], accl[R];
  float blc = ldf(bl, c, fl32);
  #pragma unroll
  for (int r = 0; r < R; ++r) { accg[r] = 0.0f; accl[r] = blc; }
  for (int k = 0; k < DIM; ++k) {
    float wg = ldf(Wg, k * DIM + c, fl32);
    float wl = ldf(Wl, k * DIM + c, fl32);
    #pragma unroll
    for (int r = 0; r < R; ++r) {
      accg[r] = fmaf(xs[r][k], wg, accg[r]);
      accl[r] = fmaf(xs[r][k], wl, accl[r]);
    }
  }
  for (int r = 0; r < R; ++r) {
    int row = r0 + r;
    if (row < N) {
      float ag = accg[r], al = accl[r];
      if (!isfinite(ag)) ag = 0.0f;
      if (!isfinite(al)) al = 0.0f;
      xw[(size_t)row * DIM + c] = f2us(ag);
      xl[(size_t)row * DIM + c] = f2us(al);
    }
  }
}

__global__ void k_gcn_agg(const int* __restrict__ src, const int* __restrict__ dst,
                          const void* __restrict__ ew, const float* __restrict__ dis,
                          const unsigned short* __restrict__ xw, float* __restrict__ h, int E,
                          const int* __restrict__ df) {
  const int fl32 = *df;
  long t = (long)blockIdx.x * blockDim.x + threadIdx.x;
  int e = (int)(t >> 5);
  if (e >= E) return;
  int lane = (int)(t & 31);
  int s = src[e], d = dst[e];
  float nm = dis[s] * ldf(ew, e, fl32) * dis[d];
  if (!isfinite(nm)) nm = 0.0f;
  int c = lane * 4;
  const ushort4 xv = *(const ushort4*)(xw + (size_t)s * DIM + c);
  float* hp = h + (size_t)d * DIM + c;
  atomicAdd(hp + 0, nm * us2f(xv.x));
  atomicAdd(hp + 1, nm * us2f(xv.y));
  atomicAdd(hp + 2, nm * us2f(xv.z));
  atomicAdd(hp + 3, nm * us2f(xv.w));
}

__global__ void k_gat_logits(const int* __restrict__ src, const int* __restrict__ dst,
                             const void* __restrict__ ea, const void* __restrict__ Wed,
                             const void* __restrict__ att, const unsigned short* __restrict__ xl,
                             float* __restrict__ logits, float* __restrict__ m, int E,
                             const int* __restrict__ df) {
  const int fl32 = *df;
  long t = (long)blockIdx.x * blockDim.x + threadIdx.x;
  int e = (int)(t >> 5);
  if (e >= E) return;
  int lane = (int)(t & 31);
  int s = src[e], d = dst[e];
  float eav = ldf(ea, e, fl32);
  int c = lane * 4;
  ushort4 a4 = *(const ushort4*)(xl + (size_t)s * DIM + c);
  ushort4 b4 = *(const ushort4*)(xl + (size_t)d * DIM + c);
  float4 w4 = ldf4(Wed, c, fl32);
  float4 t4 = ldf4(att, c, fl32);
  float dot = 0.0f, z;
  z = us2f(a4.x) + us2f(b4.x) + eav * w4.x; z = (z > 0.f) ? z : 0.2f * z; dot += z * t4.x;
  z = us2f(a4.y) + us2f(b4.y) + eav * w4.y; z = (z > 0.f) ? z : 0.2f * z; dot += z * t4.y;
  z = us2f(a4.z) + us2f(b4.z) + eav * w4.z; z = (z > 0.f) ? z : 0.2f * z; dot += z * t4.z;
  z = us2f(a4.w) + us2f(b4.w) + eav * w4.w; z = (z > 0.f) ? z : 0.2f * z; dot += z * t4.w;
  dot += __shfl_xor(dot, 1);
  dot += __shfl_xor(dot, 2);
  dot += __shfl_xor(dot, 4);
  if (!isfinite(dot)) dot = 0.0f;
  if ((lane & 7) == 0) {
    int hh = lane >> 3;
    logits[(size_t)e * HEADS + hh] = dot;
    atomicMaxFloatCAS(&m[d * HEADS + hh], dot);
  }
}

__global__ void k_gat_exp(const int* __restrict__ dst, const float* __restrict__ m,
                          float* __restrict__ logits, float* __restrict__ denom, int E) {
  int i = blockIdx.x * blockDim.x + threadIdx.x;
  if (i >= E * HEADS) return;
  int e = i >> 2;
  int hh = i & 3;
  int d = dst[e];
  float mv = m[d * HEADS + hh];
  if (!(mv > -3.0e38f && mv < 3.0e38f)) mv = 0.0f;
  float arg = fminf(logits[i] - mv, 80.0f);
  float a = expf(arg);
  if (!isfinite(a)) a = 0.0f;
  logits[i] = a;
  atomicAdd(&denom[d * HEADS + hh], a);
}

__global__ void k_gat_agg(const int* __restrict__ src, const int* __restrict__ dst,
                          const unsigned short* __restrict__ xl, const float* __restrict__ logits,
                          const float* __restrict__ denom, float* __restrict__ g, int E) {
  long t = (long)blockIdx.x * blockDim.x + threadIdx.x;
  int e = (int)(t >> 5);
  if (e >= E) return;
  int lane = (int)(t & 31);
  int s = src[e], d = dst[e];
  int hh = lane >> 3;
  float a = logits[(size_t)e * HEADS + hh] / (denom[d * HEADS + hh] + 1e-16f);
  if (!isfinite(a)) a = 0.0f;
  int c = lane * 4;
  const ushort4 xv = *(const ushort4*)(xl + (size_t)s * DIM + c);
  float* gp = g + (size_t)d * DIM + c;
  atomicAdd(gp + 0, a * us2f(xv.x));
  atomicAdd(gp + 1, a * us2f(xv.y));
  atomicAdd(gp + 2, a * us2f(xv.z));
  atomicAdd(gp + 3, a * us2f(xv.w));
}

__global__ void __launch_bounds__(256)
k_stats(const float* __restrict__ buf, const void* __restrict__ bias,
        double* __restrict__ partial, long n, const int* __restrict__ df) {
  const int fl32 = *df;
  double s = 0.0, s2 = 0.0;
  long stride = (long)gridDim.x * blockDim.x;
  for (long i = (long)blockIdx.x * blockDim.x + threadIdx.x; i < n; i += stride) {
    float v = buf[i] + ldf(bias, (size_t)(i & (DIM - 1)), fl32);
    if (!isfinite(v)) v = 0.0f;
    s += v; s2 += (double)v * v;
  }
  __shared__ double ls[256], ls2[256];
  ls[threadIdx.x] = s; ls2[threadIdx.x] = s2;
  __syncthreads();
  for (int off = 128; off > 0; off >>= 1) {
    if ((int)threadIdx.x < off) {
      ls[threadIdx.x] += ls[threadIdx.x + off];
      ls2[threadIdx.x] += ls2[threadIdx.x + off];
    }
    __syncthreads();
  }
  if (threadIdx.x == 0) { partial[2 * blockIdx.x] = ls[0]; partial[2 * blockIdx.x + 1] = ls2[0]; }
}

__device__ __forceinline__ void ln_params(double S, double S2, double M, float* mu_out, float* sc_out) {
  double mu = S / M;
  double v = S2 / M - mu * mu;
  if (!(v > 0.0)) v = 0.0;
  float fmu = (float)mu;
  float sc = 1.0f / ((float)sqrt(v) + EPS);
  if (!isfinite(fmu)) fmu = 0.0f;
  if (!isfinite(sc)) sc = 0.0f;
  *mu_out = fmu; *sc_out = sc;
}

__global__ void __launch_bounds__(256)
k_fin12(const double* __restrict__ pA, const double* __restrict__ pB,
        const void* __restrict__ alpha, float* __restrict__ params, double M,
        const int* __restrict__ df) {
  const int fl32 = *df;
  __shared__ double l1[256], l2[256], l3[256], l4[256];
  double a = 0, b = 0, c = 0, d = 0;
  for (int j = threadIdx.x; j < NBLK; j += 256) {
    a += pA[2 * j]; b += pA[2 * j + 1];
    c += pB[2 * j]; d += pB[2 * j + 1];
  }
  l1[threadIdx.x] = a; l2[threadIdx.x] = b; l3[threadIdx.x] = c; l4[threadIdx.x] = d;
  __syncthreads();
  for (int off = 128; off > 0; off >>= 1) {
    if ((int)threadIdx.x < off) {
      l1[threadIdx.x] += l1[threadIdx.x + off];
      l2[threadIdx.x] += l2[threadIdx.x + off];
      l3[threadIdx.x] += l3[threadIdx.x + off];
      l4[threadIdx.x] += l4[threadIdx.x + off];
    }
    __syncthreads();
  }
  if (threadIdx.x == 0) {
    ln_params(l1[0], l2[0], M, &params[0], &params[1]);
    ln_params(l3[0], l4[0], M, &params[2], &params[3]);
    float a0 = ldf(alpha, 0, fl32), a1 = ldf(alpha, 1, fl32);
    if (!isfinite(a0)) a0 = 0.0f;
    if (!isfinite(a1)) a1 = 0.0f;
    float mx = fmaxf(a0, a1);
    float e0 = expf(a0 - mx), e1 = expf(a1 - mx);
    float inv = 1.0f / (e0 + e1);
    params[4] = e0 * inv;
    params[5] = e1 * inv;
  }
}

__global__ void __launch_bounds__(256)
k_fin3(const double* __restrict__ pC, float* __restrict__ params, double M) {
  __shared__ double l1[256], l2[256];
  double a = 0, b = 0;
  for (int j = threadIdx.x; j < NBLK; j += 256) { a += pC[2 * j]; b += pC[2 * j + 1]; }
  l1[threadIdx.x] = a; l2[threadIdx.x] = b;
  __syncthreads();
  for (int off = 128; off > 0; off >>= 1) {
    if ((int)threadIdx.x < off) {
      l1[threadIdx.x] += l1[threadIdx.x + off];
      l2[threadIdx.x] += l2[threadIdx.x + off];
    }
    __syncthreads();
  }
  if (threadIdx.x == 0) ln_params(l1[0], l2[0], M, &params[6], &params[7]);
}

__global__ void __launch_bounds__(256)
k_fuse(const void* __restrict__ x, float* h, const float* __restrict__ g,
       const void* __restrict__ b_gcn, const void* __restrict__ b_gat,
       const void* __restrict__ gcn_nw, const void* __restrict__ gcn_nb,
       const void* __restrict__ gat_nw, const void* __restrict__ gat_nb,
       const float* __restrict__ params, double* __restrict__ pC, long n,
       const int* __restrict__ df) {
  const int fl32 = *df;
  float mu1 = params[0], sc1 = params[1], mu2 = params[2], sc2 = params[3];
  float w0 = params[4], w1 = params[5];
  double s = 0.0, s2 = 0.0;
  long stride = (long)gridDim.x * blockDim.x;
  for (long i = (long)blockIdx.x * blockDim.x + threadIdx.x; i < n; i += stride) {
    size_t c = (size_t)(i & (DIM - 1));
    float xv = ldf(x, i, fl32);
    float hv = h[i] + ldf(b_gcn, c, fl32);
    float gv = g[i] + ldf(b_gat, c, fl32);
    float go = xv + gelu_exact((hv - mu1) * sc1 * ldf(gcn_nw, c, fl32) + ldf(gcn_nb, c, fl32));
    float ao = xv + gelu_exact((gv - mu2) * sc2 * ldf(gat_nw, c, fl32) + ldf(gat_nb, c, fl32));
    float f = w0 * go + w1 * ao;
    if (!isfinite(f)) f = 0.0f;
    h[i] = f;
    s += f; s2 += (double)f * f;
  }
  __shared__ double ls[256], ls2[256];
  ls[threadIdx.x] = s; ls2[threadIdx.x] = s2;
  __syncthreads();
  for (int off = 128; off > 0; off >>= 1) {
    if ((int)threadIdx.x < off) {
      ls[threadIdx.x] += ls[threadIdx.x + off];
      ls2[threadIdx.x] += ls2[threadIdx.x + off];
    }
    __syncthreads();
  }
  if (threadIdx.x == 0) { pC[2 * blockIdx.x] = ls[0]; pC[2 * blockIdx.x + 1] = ls2[0]; }
}

__global__ void k_final(const float* __restrict__ fused, const void* __restrict__ nw,
                        const void* __restrict__ nb, const float* __restrict__ params,
                        void* __restrict__ out, long n, const int* __restrict__ df) {
  const int fl32 = *df;
  long i = (long)blockIdx.x * blockDim.x + threadIdx.x;
  if (i >= n) return;
  size_t c = (size_t)(i & (DIM - 1));
  float mu = params[6], sc = params[7];
  float r = gelu_exact((fused[i] - mu) * sc * ldf(nw, c, fl32) + ldf(nb, c, fl32));
  if (!isfinite(r)) r = 0.0f;
  if (fl32) ((float*)out)[i] = r;
  else      ((unsigned short*)out)[i] = f2us(r);
}

extern "C" void kernel_launch(void* const* d_in, const int* in_sizes, int n_in,
                              void* d_out, int out_size, void* d_ws, size_t ws_size,
                              hipStream_t stream) {
  const void* x    = d_in[0];
  const int*  ei   = (const int*)d_in[1];
  const void* ew   = d_in[2];
  const void* ea   = d_in[3];
  const void* Wg   = d_in[4];
  const void* bgcn = d_in[5];
  const void* Wl   = d_in[6];
  const void* bl   = d_in[7];
  const void* Wed  = d_in[8];
  const void* att  = d_in[9];
  const void* bgat = d_in[10];
  const void* gcn_nw = d_in[11];
  const void* gcn_nb = d_in[12];
  const void* gat_nw = d_in[13];
  const void* gat_nb = d_in[14];
  const void* out_nw = d_in[15];
  const void* out_nb = d_in[16];
  const void* alpha  = d_in[17];

  const int N = in_sizes[0] / DIM;
  const int E = in_sizes[2];
  const int* src  = ei;
  const int* dstp = ei + E;
  const size_t ND = (size_t)N * DIM;

  char* ws = (char*)d_ws;
  size_t o = 0;
  auto alloc = [&](size_t bytes) { size_t r = o; o += (bytes + 255) & ~(size_t)255; return r; };
  size_t o_h     = alloc(ND * 4);
  size_t o_g     = alloc(ND * 4);
  size_t o_deg   = alloc((size_t)N * 4);
  size_t o_denom = alloc((size_t)N * HEADS * 4);
  size_t zero_end = o;
  size_t o_xw    = alloc(ND * 2);   // bf16; later aliased as logits (E*H*4 == ND*2)
  size_t o_xl    = alloc(ND * 2);
  size_t o_m     = alloc((size_t)N * HEADS * 4);
  size_t o_par   = alloc(8 * 4);
  size_t o_pA    = alloc((size_t)NBLK * 2 * 8);
  size_t o_pB    = alloc((size_t)NBLK * 2 * 8);
  size_t o_pC    = alloc((size_t)NBLK * 2 * 8);
  size_t o_flag  = alloc(4);
  (void)ws_size; (void)n_in; (void)out_size;

  float* h      = (float*)(ws + o_h);
  float* g      = (float*)(ws + o_g);
  float* deg    = (float*)(ws + o_deg);
  float* denom  = (float*)(ws + o_denom);
  unsigned short* xw = (unsigned short*)(ws + o_xw);
  unsigned short* xl = (unsigned short*)(ws + o_xl);
  float* logits = (float*)(ws + o_xw);
  float* m      = (float*)(ws + o_m);
  float* params = (float*)(ws + o_par);
  double* pA    = (double*)(ws + o_pA);
  double* pB    = (double*)(ws + o_pB);
  double* pC    = (double*)(ws + o_pC);
  int* dflag    = (int*)(ws + o_flag);

  hipMemsetAsync(ws, 0, zero_end, stream);
  k_detect<<<1, 256, 0, stream>>>((const unsigned short*)x, (long)ND, dflag);

  int NH = N * HEADS;
  k_init_minf<<<(NH + 255) / 256, 256, 0, stream>>>(m, NH);
  k_deg<<<(E + 255) / 256, 256, 0, stream>>>(dstp, ew, deg, E, dflag);
  k_dis<<<(N + 255) / 256, 256, 0, stream>>>(deg, N);
  k_gemm_dual<<<(N + 7) / 8, 128, 0, stream>>>(x, Wg, Wl, bl, xw, xl, N, dflag);

  long e32 = (long)E * 32;
  int eb = (int)((e32 + 255) / 256);
  k_gcn_agg<<<eb, 256, 0, stream>>>(src, dstp, ew, deg, xw, h, E, dflag);
  k_stats<<<NBLK, 256, 0, stream>>>(h, bgcn, pA, (long)ND, dflag);

  k_gat_logits<<<eb, 256, 0, stream>>>(src, dstp, ea, Wed, att, xl, logits, m, E, dflag);
  int EH = E * HEADS;
  k_gat_exp<<<(EH + 255) / 256, 256, 0, stream>>>(dstp, m, logits, denom, E);
  k_gat_agg<<<eb, 256, 0, stream>>>(src, dstp, xl, logits, denom, g, E);
  k_stats<<<NBLK, 256, 0, stream>>>(g, bgat, pB, (long)ND, dflag);

  k_fin12<<<1, 256, 0, stream>>>(pA, pB, alpha, params, (double)ND, dflag);
  k_fuse<<<NBLK, 256, 0, stream>>>(x, h, g, bgcn, bgat, gcn_nw, gcn_nb, gat_nw, gat_nb,
                                   params, pC, (long)ND, dflag);
  k_fin3<<<1, 256, 0, stream>>>(pC, params, (double)ND);
  k_final<<<(int)((ND + 255) / 256), 256, 0, stream>>>(h, out_nw, out_nb, params,
                                                       d_out, (long)ND, dflag);
}

// Round 4
// 780.089 us; speedup vs baseline: 4.0524x; 4.0524x over previous
//
#include <hip/hip_runtime.h>
#include <math.h>

#define DIM 128
#define HEADS 4
#define EPS 1e-5f
#define NBLK 1024

// ---------- dtype-flex helpers ----------
__device__ __forceinline__ float us2f(unsigned short u) {
  union { unsigned int i; float f; } c; c.i = ((unsigned int)u) << 16; return c.f;
}
__device__ __forceinline__ unsigned short f2us(float f) {
  union { float ff; unsigned int i; } c; c.ff = f;
  return (unsigned short)((c.i + 0x7FFFu + ((c.i >> 16) & 1u)) >> 16);
}
// fl32: 1 -> buffers hold float32, 0 -> bfloat16
__device__ __forceinline__ float ldf(const void* p, size_t i, int fl32) {
  return fl32 ? ((const float*)p)[i] : us2f(((const unsigned short*)p)[i]);
}
__device__ __forceinline__ float4 ldf4(const void* p, size_t i, int fl32) {
  if (fl32) return *(const float4*)((const float*)p + i);
  ushort4 u = *(const ushort4*)((const unsigned short*)p + i);
  return make_float4(us2f(u.x), us2f(u.y), us2f(u.z), us2f(u.w));
}
__device__ __forceinline__ float gelu_exact(float v) {
  return 0.5f * v * (1.0f + erff(v * 0.7071067811865475f));
}

// ---------- dtype detection (unchanged; proven working) ----------
__global__ void __launch_bounds__(256)
k_detect(const unsigned short* __restrict__ x, long n, int* __restrict__ dflag) {
  long lim = n < 8192 ? n : 8192;
  int bad = 0;
  for (long i = threadIdx.x; i < lim; i += 256) {
    float v = us2f(x[i]);
    float a = fabsf(v);
    if (!(a == 0.0f || (a > 1e-30f && a < 1e3f))) bad++;
  }
  __shared__ int sb[256];
  sb[threadIdx.x] = bad;
  __syncthreads();
  for (int off = 128; off > 0; off >>= 1) {
    if ((int)threadIdx.x < off) sb[threadIdx.x] += sb[threadIdx.x + off];
    __syncthreads();
  }
  if (threadIdx.x == 0) dflag[0] = (sb[0] > 32) ? 1 : 0;
}

// ---------- CSR construction ----------
__global__ void k_deg_cnt(const int* __restrict__ dst, const void* __restrict__ ew,
                          float* __restrict__ deg, int* __restrict__ cnt, int E,
                          const int* __restrict__ df) {
  const int fl32 = *df;
  int e = blockIdx.x * blockDim.x + threadIdx.x;
  if (e < E) {
    int d = dst[e];
    float w = ldf(ew, e, fl32);
    if (isfinite(w)) atomicAdd(&deg[d], w);
    atomicAdd(&cnt[d], 1);
  }
}

__global__ void k_dis(float* __restrict__ deg, int N) {
  int i = blockIdx.x * blockDim.x + threadIdx.x;
  if (i < N) {
    float d = deg[i];
    deg[i] = (d > 0.0f) ? rsqrtf(fmaxf(d, 1e-30f)) : 0.0f;
  }
}

// single-block exclusive scan: off[0..N-1], off[N]=E
__global__ void __launch_bounds__(256)
k_scan(const int* __restrict__ cnt, int* __restrict__ off, int N, int E) {
  __shared__ int part[256];
  int t = threadIdx.x;
  int chunk = (N + 255) / 256;
  int lo = t * chunk;
  int hi = lo + chunk; if (hi > N) hi = N;
  int s = 0;
  for (int i = lo; i < hi; ++i) s += cnt[i];
  part[t] = s;
  __syncthreads();
  if (t == 0) {
    int run = 0;
    for (int j = 0; j < 256; ++j) { int tmp = part[j]; part[j] = run; run += tmp; }
  }
  __syncthreads();
  int run = part[t];
  for (int i = lo; i < hi; ++i) { off[i] = run; run += cnt[i]; }
  if (t == 0) off[N] = E;
}

__global__ void k_scatter(const int* __restrict__ src, const int* __restrict__ dst,
                          const void* __restrict__ ew, const float* __restrict__ dis,
                          const int* __restrict__ off, int* __restrict__ cursor,
                          int* __restrict__ edge_pos, int* __restrict__ csr_src,
                          float* __restrict__ csr_nm, int E, const int* __restrict__ df) {
  const int fl32 = *df;
  int e = blockIdx.x * blockDim.x + threadIdx.x;
  if (e >= E) return;
  int d = dst[e], s = src[e];
  int pos = off[d] + atomicAdd(&cursor[d], 1);
  edge_pos[e] = pos;
  csr_src[pos] = s;
  float nm = dis[s] * ldf(ew, e, fl32) * dis[d];
  if (!isfinite(nm)) nm = 0.0f;
  csr_nm[pos] = nm;
}

// ---------- dual GEMM (unchanged) ----------
__global__ void __launch_bounds__(128)
k_gemm_dual(const void* __restrict__ x, const void* __restrict__ Wg,
            const void* __restrict__ Wl, const void* __restrict__ bl,
            unsigned short* __restrict__ xw, unsigned short* __restrict__ xl, int N,
            const int* __restrict__ df) {
  const int fl32 = *df;
  const int R = 8;
  __shared__ float xs[R][DIM];
  int c = threadIdx.x;
  int r0 = blockIdx.x * R;
  for (int r = 0; r < R; ++r) {
    int row = r0 + r;
    xs[r][c] = (row < N) ? ldf(x, (size_t)row * DIM + c, fl32) : 0.0f;
  }
  __syncthreads();
  float accg[R], accl[R];
  float blc = ldf(bl, c, fl32);
  #pragma unroll
  for (int r = 0; r < R; ++r) { accg[r] = 0.0f; accl[r] = blc; }
  for (int k = 0; k < DIM; ++k) {
    float wg = ldf(Wg, k * DIM + c, fl32);
    float wl = ldf(Wl, k * DIM + c, fl32);
    #pragma unroll
    for (int r = 0; r < R; ++r) {
      accg[r] = fmaf(xs[r][k], wg, accg[r]);
      accl[r] = fmaf(xs[r][k], wl, accl[r]);
    }
  }
  for (int r = 0; r < R; ++r) {
    int row = r0 + r;
    if (row < N) {
      float ag = accg[r], al = accl[r];
      if (!isfinite(ag)) ag = 0.0f;
      if (!isfinite(al)) al = 0.0f;
      xw[(size_t)row * DIM + c] = f2us(ag);
      xl[(size_t)row * DIM + c] = f2us(al);
    }
  }
}

// ---------- GCN aggregation, gather-style: one wave per dst node ----------
__global__ void __launch_bounds__(256)
k_gcn_agg_csr(const int* __restrict__ off, const int* __restrict__ csr_src,
              const float* __restrict__ csr_nm, const unsigned short* __restrict__ xw,
              float* __restrict__ h, int N) {
  int node = (int)((long)(blockIdx.x * blockDim.x + threadIdx.x) >> 6);
  if (node >= N) return;
  int lane = threadIdx.x & 63;
  int beg = off[node], end = off[node + 1];
  float a0 = 0.0f, a1 = 0.0f;
  for (int i = beg; i < end; ++i) {
    int s = csr_src[i];
    float nm = csr_nm[i];
    ushort2 v = *(const ushort2*)(xw + (size_t)s * DIM + lane * 2);
    a0 = fmaf(nm, us2f(v.x), a0);
    a1 = fmaf(nm, us2f(v.y), a1);
  }
  *(float2*)(h + (size_t)node * DIM + lane * 2) = make_float2(a0, a1);
}

// ---------- GAT logits (edge order), write to CSR slot ----------
__global__ void k_gat_logits(const int* __restrict__ src, const int* __restrict__ dst,
                             const void* __restrict__ ea, const void* __restrict__ Wed,
                             const void* __restrict__ att, const unsigned short* __restrict__ xl,
                             const int* __restrict__ edge_pos, float* __restrict__ csr_logit,
                             int E, const int* __restrict__ df) {
  const int fl32 = *df;
  long t = (long)blockIdx.x * blockDim.x + threadIdx.x;
  int e = (int)(t >> 5);
  if (e >= E) return;
  int lane = (int)(t & 31);
  int s = src[e], d = dst[e];
  float eav = ldf(ea, e, fl32);
  int c = lane * 4;
  ushort4 a4 = *(const ushort4*)(xl + (size_t)s * DIM + c);
  ushort4 b4 = *(const ushort4*)(xl + (size_t)d * DIM + c);
  float4 w4 = ldf4(Wed, c, fl32);
  float4 t4 = ldf4(att, c, fl32);
  float dot = 0.0f, z;
  z = us2f(a4.x) + us2f(b4.x) + eav * w4.x; z = (z > 0.f) ? z : 0.2f * z; dot += z * t4.x;
  z = us2f(a4.y) + us2f(b4.y) + eav * w4.y; z = (z > 0.f) ? z : 0.2f * z; dot += z * t4.y;
  z = us2f(a4.z) + us2f(b4.z) + eav * w4.z; z = (z > 0.f) ? z : 0.2f * z; dot += z * t4.z;
  z = us2f(a4.w) + us2f(b4.w) + eav * w4.w; z = (z > 0.f) ? z : 0.2f * z; dot += z * t4.w;
  dot += __shfl_xor(dot, 1);
  dot += __shfl_xor(dot, 2);
  dot += __shfl_xor(dot, 4);
  if (!isfinite(dot)) dot = 0.0f;
  if ((lane & 7) == 0) {
    int hh = lane >> 3;
    csr_logit[(size_t)edge_pos[e] * HEADS + hh] = dot;
  }
}

// ---------- GAT softmax + aggregation, one wave per dst node, no atomics ----------
__global__ void __launch_bounds__(256)
k_gat_agg_csr(const int* __restrict__ off, const int* __restrict__ csr_src,
              const float* __restrict__ csr_logit, const unsigned short* __restrict__ xl,
              float* __restrict__ g, int N) {
  int node = (int)((long)(blockIdx.x * blockDim.x + threadIdx.x) >> 6);
  if (node >= N) return;
  int lane = threadIdx.x & 63;
  int head = lane >> 4;  // lane covers channels 2*lane,2*lane+1 -> head = lane/16
  int beg = off[node], end = off[node + 1];
  float mx = -INFINITY;
  for (int i = beg; i < end; ++i) mx = fmaxf(mx, csr_logit[(size_t)i * HEADS + head]);
  float den = 0.0f;
  for (int i = beg; i < end; ++i) den += expf(csr_logit[(size_t)i * HEADS + head] - mx);
  float inv = (end > beg) ? 1.0f / (den + 1e-16f) : 0.0f;
  float a0 = 0.0f, a1 = 0.0f;
  for (int i = beg; i < end; ++i) {
    float w = expf(csr_logit[(size_t)i * HEADS + head] - mx) * inv;
    int s = csr_src[i];
    ushort2 v = *(const ushort2*)(xl + (size_t)s * DIM + lane * 2);
    a0 = fmaf(w, us2f(v.x), a0);
    a1 = fmaf(w, us2f(v.y), a1);
  }
  if (!isfinite(a0)) a0 = 0.0f;
  if (!isfinite(a1)) a1 = 0.0f;
  *(float2*)(g + (size_t)node * DIM + lane * 2) = make_float2(a0, a1);
}

// ---------- LN stats / finalize / fuse / output (unchanged) ----------
__global__ void __launch_bounds__(256)
k_stats(const float* __restrict__ buf, const void* __restrict__ bias,
        double* __restrict__ partial, long n, const int* __restrict__ df) {
  const int fl32 = *df;
  double s = 0.0, s2 = 0.0;
  long stride = (long)gridDim.x * blockDim.x;
  for (long i = (long)blockIdx.x * blockDim.x + threadIdx.x; i < n; i += stride) {
    float v = buf[i] + ldf(bias, (size_t)(i & (DIM - 1)), fl32);
    if (!isfinite(v)) v = 0.0f;
    s += v; s2 += (double)v * v;
  }
  __shared__ double ls[256], ls2[256];
  ls[threadIdx.x] = s; ls2[threadIdx.x] = s2;
  __syncthreads();
  for (int off = 128; off > 0; off >>= 1) {
    if ((int)threadIdx.x < off) {
      ls[threadIdx.x] += ls[threadIdx.x + off];
      ls2[threadIdx.x] += ls2[threadIdx.x + off];
    }
    __syncthreads();
  }
  if (threadIdx.x == 0) { partial[2 * blockIdx.x] = ls[0]; partial[2 * blockIdx.x + 1] = ls2[0]; }
}

__device__ __forceinline__ void ln_params(double S, double S2, double M, float* mu_out, float* sc_out) {
  double mu = S / M;
  double v = S2 / M - mu * mu;
  if (!(v > 0.0)) v = 0.0;
  float fmu = (float)mu;
  float sc = 1.0f / ((float)sqrt(v) + EPS);
  if (!isfinite(fmu)) fmu = 0.0f;
  if (!isfinite(sc)) sc = 0.0f;
  *mu_out = fmu; *sc_out = sc;
}

__global__ void __launch_bounds__(256)
k_fin12(const double* __restrict__ pA, const double* __restrict__ pB,
        const void* __restrict__ alpha, float* __restrict__ params, double M,
        const int* __restrict__ df) {
  const int fl32 = *df;
  __shared__ double l1[256], l2[256], l3[256], l4[256];
  double a = 0, b = 0, c = 0, d = 0;
  for (int j = threadIdx.x; j < NBLK; j += 256) {
    a += pA[2 * j]; b += pA[2 * j + 1];
    c += pB[2 * j]; d += pB[2 * j + 1];
  }
  l1[threadIdx.x] = a; l2[threadIdx.x] = b; l3[threadIdx.x] = c; l4[threadIdx.x] = d;
  __syncthreads();
  for (int off = 128; off > 0; off >>= 1) {
    if ((int)threadIdx.x < off) {
      l1[threadIdx.x] += l1[threadIdx.x + off];
      l2[threadIdx.x] += l2[threadIdx.x + off];
      l3[threadIdx.x] += l3[threadIdx.x + off];
      l4[threadIdx.x] += l4[threadIdx.x + off];
    }
    __syncthreads();
  }
  if (threadIdx.x == 0) {
    ln_params(l1[0], l2[0], M, &params[0], &params[1]);
    ln_params(l3[0], l4[0], M, &params[2], &params[3]);
    float a0 = ldf(alpha, 0, fl32), a1 = ldf(alpha, 1, fl32);
    if (!isfinite(a0)) a0 = 0.0f;
    if (!isfinite(a1)) a1 = 0.0f;
    float mx = fmaxf(a0, a1);
    float e0 = expf(a0 - mx), e1 = expf(a1 - mx);
    float inv = 1.0f / (e0 + e1);
    params[4] = e0 * inv;
    params[5] = e1 * inv;
  }
}

__global__ void __launch_bounds__(256)
k_fin3(const double* __restrict__ pC, float* __restrict__ params, double M) {
  __shared__ double l1[256], l2[256];
  double a = 0, b = 0;
  for (int j = threadIdx.x; j < NBLK; j += 256) { a += pC[2 * j]; b += pC[2 * j + 1]; }
  l1[threadIdx.x] = a; l2[threadIdx.x] = b;
  __syncthreads();
  for (int off = 128; off > 0; off >>= 1) {
    if ((int)threadIdx.x < off) {
      l1[threadIdx.x] += l1[threadIdx.x + off];
      l2[threadIdx.x] += l2[threadIdx.x + off];
    }
    __syncthreads();
  }
  if (threadIdx.x == 0) ln_params(l1[0], l2[0], M, &params[6], &params[7]);
}

__global__ void __launch_bounds__(256)
k_fuse(const void* __restrict__ x, float* h, const float* __restrict__ g,
       const void* __restrict__ b_gcn, const void* __restrict__ b_gat,
       const void* __restrict__ gcn_nw, const void* __restrict__ gcn_nb,
       const void* __restrict__ gat_nw, const void* __restrict__ gat_nb,
       const float* __restrict__ params, double* __restrict__ pC, long n,
       const int* __restrict__ df) {
  const int fl32 = *df;
  float mu1 = params[0], sc1 = params[1], mu2 = params[2], sc2 = params[3];
  float w0 = params[4], w1 = params[5];
  double s = 0.0, s2 = 0.0;
  long stride = (long)gridDim.x * blockDim.x;
  for (long i = (long)blockIdx.x * blockDim.x + threadIdx.x; i < n; i += stride) {
    size_t c = (size_t)(i & (DIM - 1));
    float xv = ldf(x, i, fl32);
    float hv = h[i] + ldf(b_gcn, c, fl32);
    float gv = g[i] + ldf(b_gat, c, fl32);
    float go = xv + gelu_exact((hv - mu1) * sc1 * ldf(gcn_nw, c, fl32) + ldf(gcn_nb, c, fl32));
    float ao = xv + gelu_exact((gv - mu2) * sc2 * ldf(gat_nw, c, fl32) + ldf(gat_nb, c, fl32));
    float f = w0 * go + w1 * ao;
    if (!isfinite(f)) f = 0.0f;
    h[i] = f;
    s += f; s2 += (double)f * f;
  }
  __shared__ double ls[256], ls2[256];
  ls[threadIdx.x] = s; ls2[threadIdx.x] = s2;
  __syncthreads();
  for (int off = 128; off > 0; off >>= 1) {
    if ((int)threadIdx.x < off) {
      ls[threadIdx.x] += ls[threadIdx.x + off];
      ls2[threadIdx.x] += ls2[threadIdx.x + off];
    }
    __syncthreads();
  }
  if (threadIdx.x == 0) { pC[2 * blockIdx.x] = ls[0]; pC[2 * blockIdx.x + 1] = ls2[0]; }
}

__global__ void k_final(const float* __restrict__ fused, const void* __restrict__ nw,
                        const void* __restrict__ nb, const float* __restrict__ params,
                        void* __restrict__ out, long n, const int* __restrict__ df) {
  const int fl32 = *df;
  long i = (long)blockIdx.x * blockDim.x + threadIdx.x;
  if (i >= n) return;
  size_t c = (size_t)(i & (DIM - 1));
  float mu = params[6], sc = params[7];
  float r = gelu_exact((fused[i] - mu) * sc * ldf(nw, c, fl32) + ldf(nb, c, fl32));
  if (!isfinite(r)) r = 0.0f;
  if (fl32) ((float*)out)[i] = r;
  else      ((unsigned short*)out)[i] = f2us(r);
}

extern "C" void kernel_launch(void* const* d_in, const int* in_sizes, int n_in,
                              void* d_out, int out_size, void* d_ws, size_t ws_size,
                              hipStream_t stream) {
  const void* x    = d_in[0];
  const int*  ei   = (const int*)d_in[1];
  const void* ew   = d_in[2];
  const void* ea   = d_in[3];
  const void* Wg   = d_in[4];
  const void* bgcn = d_in[5];
  const void* Wl   = d_in[6];
  const void* bl   = d_in[7];
  const void* Wed  = d_in[8];
  const void* att  = d_in[9];
  const void* bgat = d_in[10];
  const void* gcn_nw = d_in[11];
  const void* gcn_nb = d_in[12];
  const void* gat_nw = d_in[13];
  const void* gat_nb = d_in[14];
  const void* out_nw = d_in[15];
  const void* out_nb = d_in[16];
  const void* alpha  = d_in[17];

  const int N = in_sizes[0] / DIM;
  const int E = in_sizes[2];
  const int* src  = ei;
  const int* dstp = ei + E;
  const size_t ND = (size_t)N * DIM;

  char* ws = (char*)d_ws;
  size_t o = 0;
  auto alloc = [&](size_t bytes) { size_t r = o; o += (bytes + 255) & ~(size_t)255; return r; };
  size_t o_deg    = alloc((size_t)N * 4);
  size_t o_cnt    = alloc((size_t)N * 4);
  size_t o_cursor = alloc((size_t)N * 4);
  size_t zero_end = o;                         // [0, zero_end) memset to 0
  size_t o_off    = alloc((size_t)(N + 1) * 4);
  size_t o_h      = alloc(ND * 4);
  size_t o_g      = alloc(ND * 4);
  size_t o_xw     = alloc(ND * 2);             // bf16; aliased as csr_logit (E*H*4 == ND*2)
  size_t o_xl     = alloc(ND * 2);
  size_t o_epos   = alloc((size_t)E * 4);
  size_t o_csrc   = alloc((size_t)E * 4);
  size_t o_cnm    = alloc((size_t)E * 4);
  size_t o_par    = alloc(8 * 4);
  size_t o_pA     = alloc((size_t)NBLK * 2 * 8);
  size_t o_pB     = alloc((size_t)NBLK * 2 * 8);
  size_t o_pC     = alloc((size_t)NBLK * 2 * 8);
  size_t o_flag   = alloc(4);
  (void)ws_size; (void)n_in; (void)out_size;

  float* deg     = (float*)(ws + o_deg);
  int*   cnt     = (int*)(ws + o_cnt);
  int*   cursor  = (int*)(ws + o_cursor);
  int*   off     = (int*)(ws + o_off);
  float* h       = (float*)(ws + o_h);
  float* g       = (float*)(ws + o_g);
  unsigned short* xw = (unsigned short*)(ws + o_xw);
  unsigned short* xl = (unsigned short*)(ws + o_xl);
  float* csr_logit = (float*)(ws + o_xw);      // alias: xw dead before logits born
  int*   edge_pos  = (int*)(ws + o_epos);
  int*   csr_src   = (int*)(ws + o_csrc);
  float* csr_nm    = (float*)(ws + o_cnm);
  float* params  = (float*)(ws + o_par);
  double* pA     = (double*)(ws + o_pA);
  double* pB     = (double*)(ws + o_pB);
  double* pC     = (double*)(ws + o_pC);
  int* dflag     = (int*)(ws + o_flag);

  hipMemsetAsync(ws, 0, zero_end, stream);
  k_detect<<<1, 256, 0, stream>>>((const unsigned short*)x, (long)ND, dflag);

  int ebk = (E + 255) / 256;
  k_deg_cnt<<<ebk, 256, 0, stream>>>(dstp, ew, deg, cnt, E, dflag);
  k_dis<<<(N + 255) / 256, 256, 0, stream>>>(deg, N);
  k_scan<<<1, 256, 0, stream>>>(cnt, off, N, E);
  k_scatter<<<ebk, 256, 0, stream>>>(src, dstp, ew, deg, off, cursor,
                                     edge_pos, csr_src, csr_nm, E, dflag);

  k_gemm_dual<<<(N + 7) / 8, 128, 0, stream>>>(x, Wg, Wl, bl, xw, xl, N, dflag);

  int nwaveblk = (N + 3) / 4;  // 4 waves (nodes) per 256-thread block
  k_gcn_agg_csr<<<nwaveblk, 256, 0, stream>>>(off, csr_src, csr_nm, xw, h, N);
  k_stats<<<NBLK, 256, 0, stream>>>(h, bgcn, pA, (long)ND, dflag);

  long e32 = (long)E * 32;
  k_gat_logits<<<(int)((e32 + 255) / 256), 256, 0, stream>>>(src, dstp, ea, Wed, att, xl,
                                                             edge_pos, csr_logit, E, dflag);
  k_gat_agg_csr<<<nwaveblk, 256, 0, stream>>>(off, csr_src, csr_logit, xl, g, N);
  k_stats<<<NBLK, 256, 0, stream>>>(g, bgat, pB, (long)ND, dflag);

  k_fin12<<<1, 256, 0, stream>>>(pA, pB, alpha, params, (double)ND, dflag);
  k_fuse<<<NBLK, 256, 0, stream>>>(x, h, g, bgcn, bgat, gcn_nw, gcn_nb, gat_nw, gat_nb,
                                   params, pC, (long)ND, dflag);
  k_fin3<<<1, 256, 0, stream>>>(pC, params, (double)ND);
  k_final<<<(int)((ND + 255) / 256), 256, 0, stream>>>(h, out_nw, out_nb, params,
                                                       d_out, (long)ND, dflag);
}

// Round 5
// 677.487 us; speedup vs baseline: 4.6661x; 1.1514x over previous
//
#include <hip/hip_runtime.h>
#include <math.h>

#define DIM 128
#define HEADS 4
#define EPS 1e-5f
#define NBLK 1024

// ---------- dtype-flex helpers ----------
__device__ __forceinline__ float us2f(unsigned short u) {
  union { unsigned int i; float f; } c; c.i = ((unsigned int)u) << 16; return c.f;
}
__device__ __forceinline__ unsigned short f2us(float f) {
  union { float ff; unsigned int i; } c; c.ff = f;
  return (unsigned short)((c.i + 0x7FFFu + ((c.i >> 16) & 1u)) >> 16);
}
// fl32: 1 -> buffers hold float32, 0 -> bfloat16
__device__ __forceinline__ float ldf(const void* p, size_t i, int fl32) {
  return fl32 ? ((const float*)p)[i] : us2f(((const unsigned short*)p)[i]);
}
__device__ __forceinline__ float gelu_exact(float v) {
  return 0.5f * v * (1.0f + erff(v * 0.7071067811865475f));
}

// ---------- dtype detection (proven) ----------
__global__ void __launch_bounds__(256)
k_detect(const unsigned short* __restrict__ x, long n, int* __restrict__ dflag) {
  long lim = n < 8192 ? n : 8192;
  int bad = 0;
  for (long i = threadIdx.x; i < lim; i += 256) {
    float v = us2f(x[i]);
    float a = fabsf(v);
    if (!(a == 0.0f || (a > 1e-30f && a < 1e3f))) bad++;
  }
  __shared__ int sb[256];
  sb[threadIdx.x] = bad;
  __syncthreads();
  for (int off = 128; off > 0; off >>= 1) {
    if ((int)threadIdx.x < off) sb[threadIdx.x] += sb[threadIdx.x + off];
    __syncthreads();
  }
  if (threadIdx.x == 0) dflag[0] = (sb[0] > 32) ? 1 : 0;
}

// ---------- CSR construction ----------
__global__ void k_deg_cnt(const int* __restrict__ dst, const void* __restrict__ ew,
                          float* __restrict__ deg, int* __restrict__ cnt, int E,
                          const int* __restrict__ df) {
  const int fl32 = *df;
  int e = blockIdx.x * blockDim.x + threadIdx.x;
  if (e < E) {
    int d = dst[e];
    float w = ldf(ew, e, fl32);
    if (isfinite(w)) atomicAdd(&deg[d], w);
    atomicAdd(&cnt[d], 1);
  }
}

__global__ void k_dis(float* __restrict__ deg, int N) {
  int i = blockIdx.x * blockDim.x + threadIdx.x;
  if (i < N) {
    float d = deg[i];
    deg[i] = (d > 0.0f) ? rsqrtf(fmaxf(d, 1e-30f)) : 0.0f;
  }
}

__global__ void __launch_bounds__(256)
k_scan(const int* __restrict__ cnt, int* __restrict__ off, int N, int E) {
  __shared__ int part[256];
  int t = threadIdx.x;
  int chunk = (N + 255) / 256;
  int lo = t * chunk;
  int hi = lo + chunk; if (hi > N) hi = N;
  int s = 0;
  for (int i = lo; i < hi; ++i) s += cnt[i];
  part[t] = s;
  __syncthreads();
  if (t == 0) {
    int run = 0;
    for (int j = 0; j < 256; ++j) { int tmp = part[j]; part[j] = run; run += tmp; }
  }
  __syncthreads();
  int run = part[t];
  for (int i = lo; i < hi; ++i) { off[i] = run; run += cnt[i]; }
  if (t == 0) off[N] = E;
}

__global__ void k_scatter(const int* __restrict__ src, const int* __restrict__ dst,
                          const void* __restrict__ ew, const void* __restrict__ ea,
                          const float* __restrict__ dis, const int* __restrict__ off,
                          int* __restrict__ cursor, int* __restrict__ csr_src,
                          float* __restrict__ csr_nm, float* __restrict__ csr_ea,
                          int E, const int* __restrict__ df) {
  const int fl32 = *df;
  int e = blockIdx.x * blockDim.x + threadIdx.x;
  if (e >= E) return;
  int d = dst[e], s = src[e];
  int pos = off[d] + atomicAdd(&cursor[d], 1);
  csr_src[pos] = s;
  float nm = dis[s] * ldf(ew, e, fl32) * dis[d];
  if (!isfinite(nm)) nm = 0.0f;
  csr_nm[pos] = nm;
  float eav = ldf(ea, e, fl32);
  if (!isfinite(eav)) eav = 0.0f;
  csr_ea[pos] = eav;
}

// ---------- dual GEMM (unchanged) ----------
__global__ void __launch_bounds__(128)
k_gemm_dual(const void* __restrict__ x, const void* __restrict__ Wg,
            const void* __restrict__ Wl, const void* __restrict__ bl,
            unsigned short* __restrict__ xw, unsigned short* __restrict__ xl, int N,
            const int* __restrict__ df) {
  const int fl32 = *df;
  const int R = 8;
  __shared__ float xs[R][DIM];
  int c = threadIdx.x;
  int r0 = blockIdx.x * R;
  for (int r = 0; r < R; ++r) {
    int row = r0 + r;
    xs[r][c] = (row < N) ? ldf(x, (size_t)row * DIM + c, fl32) : 0.0f;
  }
  __syncthreads();
  float accg[R], accl[R];
  float blc = ldf(bl, c, fl32);
  #pragma unroll
  for (int r = 0; r < R; ++r) { accg[r] = 0.0f; accl[r] = blc; }
  for (int k = 0; k < DIM; ++k) {
    float wg = ldf(Wg, k * DIM + c, fl32);
    float wl = ldf(Wl, k * DIM + c, fl32);
    #pragma unroll
    for (int r = 0; r < R; ++r) {
      accg[r] = fmaf(xs[r][k], wg, accg[r]);
      accl[r] = fmaf(xs[r][k], wl, accl[r]);
    }
  }
  for (int r = 0; r < R; ++r) {
    int row = r0 + r;
    if (row < N) {
      float ag = accg[r], al = accl[r];
      if (!isfinite(ag)) ag = 0.0f;
      if (!isfinite(al)) al = 0.0f;
      xw[(size_t)row * DIM + c] = f2us(ag);
      xl[(size_t)row * DIM + c] = f2us(al);
    }
  }
}

// ---------- MEGA: GCN agg + GATv2 logits+softmax+agg + both LN stats ----------
// one wave per node; lane owns channels (2*lane, 2*lane+1); head = lane/16
__global__ void __launch_bounds__(256)
k_mega(const int* __restrict__ off, const int* __restrict__ csr_src,
       const float* __restrict__ csr_nm, const float* __restrict__ csr_ea,
       const unsigned short* __restrict__ xw, const unsigned short* __restrict__ xl,
       const void* __restrict__ Wed, const void* __restrict__ att,
       const void* __restrict__ bgcn, const void* __restrict__ bgat,
       float* __restrict__ h, float* __restrict__ g,
       double* __restrict__ pA, double* __restrict__ pB, int N,
       const int* __restrict__ df) {
  const int fl32 = *df;
  int wid = threadIdx.x >> 6;
  int lane = threadIdx.x & 63;
  int node = blockIdx.x * 4 + wid;
  int c0 = lane * 2;
  float wd0 = ldf(Wed, c0, fl32), wd1 = ldf(Wed, c0 + 1, fl32);
  float at0 = ldf(att, c0, fl32), at1 = ldf(att, c0 + 1, fl32);
  double sA = 0.0, sA2 = 0.0, sB = 0.0, sB2 = 0.0;
  if (node < N) {
    int beg = off[node], end = off[node + 1];
    float xd0 = us2f(xl[(size_t)node * DIM + c0]);
    float xd1 = us2f(xl[(size_t)node * DIM + c0 + 1]);
    // pass A: logits max
    float mx = -INFINITY;
    for (int i = beg; i < end; ++i) {
      int s = csr_src[i];
      float eav = csr_ea[i];
      ushort2 v = *(const ushort2*)(xl + (size_t)s * DIM + c0);
      float z0 = xd0 + us2f(v.x) + eav * wd0; z0 = (z0 > 0.f) ? z0 : 0.2f * z0;
      float z1 = xd1 + us2f(v.y) + eav * wd1; z1 = (z1 > 0.f) ? z1 : 0.2f * z1;
      float dot = z0 * at0 + z1 * at1;
      dot += __shfl_xor(dot, 1);
      dot += __shfl_xor(dot, 2);
      dot += __shfl_xor(dot, 4);
      dot += __shfl_xor(dot, 8);
      mx = fmaxf(mx, dot);
    }
    // pass B: recompute logit; exp + denom + GAT acc + GCN acc
    float den = 0.f, ga0 = 0.f, ga1 = 0.f, hc0 = 0.f, hc1 = 0.f;
    for (int i = beg; i < end; ++i) {
      int s = csr_src[i];
      float eav = csr_ea[i];
      float nm = csr_nm[i];
      ushort2 v = *(const ushort2*)(xl + (size_t)s * DIM + c0);
      ushort2 u = *(const ushort2*)(xw + (size_t)s * DIM + c0);
      float z0 = xd0 + us2f(v.x) + eav * wd0; z0 = (z0 > 0.f) ? z0 : 0.2f * z0;
      float z1 = xd1 + us2f(v.y) + eav * wd1; z1 = (z1 > 0.f) ? z1 : 0.2f * z1;
      float dot = z0 * at0 + z1 * at1;
      dot += __shfl_xor(dot, 1);
      dot += __shfl_xor(dot, 2);
      dot += __shfl_xor(dot, 4);
      dot += __shfl_xor(dot, 8);
      float w = __expf(dot - mx);   // dot-mx <= 0 by construction (identical recompute)
      den += w;
      ga0 = fmaf(w, us2f(v.x), ga0);
      ga1 = fmaf(w, us2f(v.y), ga1);
      hc0 = fmaf(nm, us2f(u.x), hc0);
      hc1 = fmaf(nm, us2f(u.y), hc1);
    }
    float inv = (end > beg) ? 1.0f / (den + 1e-16f) : 0.0f;
    ga0 *= inv; ga1 *= inv;
    if (!isfinite(ga0)) ga0 = 0.0f;
    if (!isfinite(ga1)) ga1 = 0.0f;
    if (!isfinite(hc0)) hc0 = 0.0f;
    if (!isfinite(hc1)) hc1 = 0.0f;
    *(float2*)(h + (size_t)node * DIM + c0) = make_float2(hc0, hc1);
    *(float2*)(g + (size_t)node * DIM + c0) = make_float2(ga0, ga1);
    // LN stats contributions (with conv biases, matching reference h+b / g+b)
    float hA0 = hc0 + ldf(bgcn, c0, fl32), hA1 = hc1 + ldf(bgcn, c0 + 1, fl32);
    float gB0 = ga0 + ldf(bgat, c0, fl32), gB1 = ga1 + ldf(bgat, c0 + 1, fl32);
    sA  = (double)hA0 + (double)hA1;
    sA2 = (double)hA0 * hA0 + (double)hA1 * hA1;
    sB  = (double)gB0 + (double)gB1;
    sB2 = (double)gB0 * gB0 + (double)gB1 * gB1;
  }
  __shared__ double l1[256], l2[256], l3[256], l4[256];
  l1[threadIdx.x] = sA; l2[threadIdx.x] = sA2; l3[threadIdx.x] = sB; l4[threadIdx.x] = sB2;
  __syncthreads();
  for (int o = 128; o > 0; o >>= 1) {
    if ((int)threadIdx.x < o) {
      l1[threadIdx.x] += l1[threadIdx.x + o];
      l2[threadIdx.x] += l2[threadIdx.x + o];
      l3[threadIdx.x] += l3[threadIdx.x + o];
      l4[threadIdx.x] += l4[threadIdx.x + o];
    }
    __syncthreads();
  }
  if (threadIdx.x == 0) {
    pA[2 * blockIdx.x] = l1[0]; pA[2 * blockIdx.x + 1] = l2[0];
    pB[2 * blockIdx.x] = l3[0]; pB[2 * blockIdx.x + 1] = l4[0];
  }
}

// ---------- LN finalize / fuse / output ----------
__device__ __forceinline__ void ln_params(double S, double S2, double M, float* mu_out, float* sc_out) {
  double mu = S / M;
  double v = S2 / M - mu * mu;
  if (!(v > 0.0)) v = 0.0;
  float fmu = (float)mu;
  float sc = 1.0f / ((float)sqrt(v) + EPS);
  if (!isfinite(fmu)) fmu = 0.0f;
  if (!isfinite(sc)) sc = 0.0f;
  *mu_out = fmu; *sc_out = sc;
}

__global__ void __launch_bounds__(256)
k_fin12(const double* __restrict__ pA, const double* __restrict__ pB, int nblk,
        const void* __restrict__ alpha, float* __restrict__ params, double M,
        const int* __restrict__ df) {
  const int fl32 = *df;
  __shared__ double l1[256], l2[256], l3[256], l4[256];
  double a = 0, b = 0, c = 0, d = 0;
  for (int j = threadIdx.x; j < nblk; j += 256) {
    a += pA[2 * j]; b += pA[2 * j + 1];
    c += pB[2 * j]; d += pB[2 * j + 1];
  }
  l1[threadIdx.x] = a; l2[threadIdx.x] = b; l3[threadIdx.x] = c; l4[threadIdx.x] = d;
  __syncthreads();
  for (int off = 128; off > 0; off >>= 1) {
    if ((int)threadIdx.x < off) {
      l1[threadIdx.x] += l1[threadIdx.x + off];
      l2[threadIdx.x] += l2[threadIdx.x + off];
      l3[threadIdx.x] += l3[threadIdx.x + off];
      l4[threadIdx.x] += l4[threadIdx.x + off];
    }
    __syncthreads();
  }
  if (threadIdx.x == 0) {
    ln_params(l1[0], l2[0], M, &params[0], &params[1]);
    ln_params(l3[0], l4[0], M, &params[2], &params[3]);
    float a0 = ldf(alpha, 0, fl32), a1 = ldf(alpha, 1, fl32);
    if (!isfinite(a0)) a0 = 0.0f;
    if (!isfinite(a1)) a1 = 0.0f;
    float mx = fmaxf(a0, a1);
    float e0 = expf(a0 - mx), e1 = expf(a1 - mx);
    float inv = 1.0f / (e0 + e1);
    params[4] = e0 * inv;
    params[5] = e1 * inv;
  }
}

__global__ void __launch_bounds__(256)
k_fin3(const double* __restrict__ pC, float* __restrict__ params, double M) {
  __shared__ double l1[256], l2[256];
  double a = 0, b = 0;
  for (int j = threadIdx.x; j < NBLK; j += 256) { a += pC[2 * j]; b += pC[2 * j + 1]; }
  l1[threadIdx.x] = a; l2[threadIdx.x] = b;
  __syncthreads();
  for (int off = 128; off > 0; off >>= 1) {
    if ((int)threadIdx.x < off) {
      l1[threadIdx.x] += l1[threadIdx.x + off];
      l2[threadIdx.x] += l2[threadIdx.x + off];
    }
    __syncthreads();
  }
  if (threadIdx.x == 0) ln_params(l1[0], l2[0], M, &params[6], &params[7]);
}

__global__ void __launch_bounds__(256)
k_fuse(const void* __restrict__ x, float* h, const float* __restrict__ g,
       const void* __restrict__ b_gcn, const void* __restrict__ b_gat,
       const void* __restrict__ gcn_nw, const void* __restrict__ gcn_nb,
       const void* __restrict__ gat_nw, const void* __restrict__ gat_nb,
       const float* __restrict__ params, double* __restrict__ pC, long n,
       const int* __restrict__ df) {
  const int fl32 = *df;
  float mu1 = params[0], sc1 = params[1], mu2 = params[2], sc2 = params[3];
  float w0 = params[4], w1 = params[5];
  double s = 0.0, s2 = 0.0;
  long stride = (long)gridDim.x * blockDim.x;
  for (long i = (long)blockIdx.x * blockDim.x + threadIdx.x; i < n; i += stride) {
    size_t c = (size_t)(i & (DIM - 1));
    float xv = ldf(x, i, fl32);
    float hv = h[i] + ldf(b_gcn, c, fl32);
    float gv = g[i] + ldf(b_gat, c, fl32);
    float go = xv + gelu_exact((hv - mu1) * sc1 * ldf(gcn_nw, c, fl32) + ldf(gcn_nb, c, fl32));
    float ao = xv + gelu_exact((gv - mu2) * sc2 * ldf(gat_nw, c, fl32) + ldf(gat_nb, c, fl32));
    float f = w0 * go + w1 * ao;
    if (!isfinite(f)) f = 0.0f;
    h[i] = f;
    s += f; s2 += (double)f * f;
  }
  __shared__ double ls[256], ls2[256];
  ls[threadIdx.x] = s; ls2[threadIdx.x] = s2;
  __syncthreads();
  for (int off = 128; off > 0; off >>= 1) {
    if ((int)threadIdx.x < off) {
      ls[threadIdx.x] += ls[threadIdx.x + off];
      ls2[threadIdx.x] += ls2[threadIdx.x + off];
    }
    __syncthreads();
  }
  if (threadIdx.x == 0) { pC[2 * blockIdx.x] = ls[0]; pC[2 * blockIdx.x + 1] = ls2[0]; }
}

__global__ void k_final(const float* __restrict__ fused, const void* __restrict__ nw,
                        const void* __restrict__ nb, const float* __restrict__ params,
                        void* __restrict__ out, long n, const int* __restrict__ df) {
  const int fl32 = *df;
  long i = (long)blockIdx.x * blockDim.x + threadIdx.x;
  if (i >= n) return;
  size_t c = (size_t)(i & (DIM - 1));
  float mu = params[6], sc = params[7];
  float r = gelu_exact((fused[i] - mu) * sc * ldf(nw, c, fl32) + ldf(nb, c, fl32));
  if (!isfinite(r)) r = 0.0f;
  if (fl32) ((float*)out)[i] = r;
  else      ((unsigned short*)out)[i] = f2us(r);
}

extern "C" void kernel_launch(void* const* d_in, const int* in_sizes, int n_in,
                              void* d_out, int out_size, void* d_ws, size_t ws_size,
                              hipStream_t stream) {
  const void* x    = d_in[0];
  const int*  ei   = (const int*)d_in[1];
  const void* ew   = d_in[2];
  const void* ea   = d_in[3];
  const void* Wg   = d_in[4];
  const void* bgcn = d_in[5];
  const void* Wl   = d_in[6];
  const void* bl   = d_in[7];
  const void* Wed  = d_in[8];
  const void* att  = d_in[9];
  const void* bgat = d_in[10];
  const void* gcn_nw = d_in[11];
  const void* gcn_nb = d_in[12];
  const void* gat_nw = d_in[13];
  const void* gat_nb = d_in[14];
  const void* out_nw = d_in[15];
  const void* out_nb = d_in[16];
  const void* alpha  = d_in[17];

  const int N = in_sizes[0] / DIM;
  const int E = in_sizes[2];
  const int* src  = ei;
  const int* dstp = ei + E;
  const size_t ND = (size_t)N * DIM;
  const int nAgg = (N + 3) / 4;  // mega grid (4 waves/block)

  char* ws = (char*)d_ws;
  size_t o = 0;
  auto alloc = [&](size_t bytes) { size_t r = o; o += (bytes + 255) & ~(size_t)255; return r; };
  size_t o_deg    = alloc((size_t)N * 4);
  size_t o_cnt    = alloc((size_t)N * 4);
  size_t o_cursor = alloc((size_t)N * 4);
  size_t zero_end = o;                         // [0, zero_end) memset to 0
  size_t o_off    = alloc((size_t)(N + 1) * 4);
  size_t o_h      = alloc(ND * 4);
  size_t o_g      = alloc(ND * 4);
  size_t o_xw     = alloc(ND * 2);
  size_t o_xl     = alloc(ND * 2);
  size_t o_csrc   = alloc((size_t)E * 4);
  size_t o_cnm    = alloc((size_t)E * 4);
  size_t o_cea    = alloc((size_t)E * 4);
  size_t o_par    = alloc(8 * 4);
  size_t o_pA     = alloc((size_t)nAgg * 2 * 8);
  size_t o_pB     = alloc((size_t)nAgg * 2 * 8);
  size_t o_pC     = alloc((size_t)NBLK * 2 * 8);
  size_t o_flag   = alloc(4);
  (void)ws_size; (void)n_in; (void)out_size;

  float* deg     = (float*)(ws + o_deg);
  int*   cnt     = (int*)(ws + o_cnt);
  int*   cursor  = (int*)(ws + o_cursor);
  int*   off     = (int*)(ws + o_off);
  float* h       = (float*)(ws + o_h);
  float* g       = (float*)(ws + o_g);
  unsigned short* xw = (unsigned short*)(ws + o_xw);
  unsigned short* xl = (unsigned short*)(ws + o_xl);
  int*   csr_src = (int*)(ws + o_csrc);
  float* csr_nm  = (float*)(ws + o_cnm);
  float* csr_ea  = (float*)(ws + o_cea);
  float* params  = (float*)(ws + o_par);
  double* pA     = (double*)(ws + o_pA);
  double* pB     = (double*)(ws + o_pB);
  double* pC     = (double*)(ws + o_pC);
  int* dflag     = (int*)(ws + o_flag);

  hipMemsetAsync(ws, 0, zero_end, stream);
  k_detect<<<1, 256, 0, stream>>>((const unsigned short*)x, (long)ND, dflag);

  int ebk = (E + 255) / 256;
  k_deg_cnt<<<ebk, 256, 0, stream>>>(dstp, ew, deg, cnt, E, dflag);
  k_dis<<<(N + 255) / 256, 256, 0, stream>>>(deg, N);
  k_scan<<<1, 256, 0, stream>>>(cnt, off, N, E);
  k_scatter<<<ebk, 256, 0, stream>>>(src, dstp, ew, ea, deg, off, cursor,
                                     csr_src, csr_nm, csr_ea, E, dflag);

  k_gemm_dual<<<(N + 7) / 8, 128, 0, stream>>>(x, Wg, Wl, bl, xw, xl, N, dflag);

  k_mega<<<nAgg, 256, 0, stream>>>(off, csr_src, csr_nm, csr_ea, xw, xl,
                                   Wed, att, bgcn, bgat, h, g, pA, pB, N, dflag);

  k_fin12<<<1, 256, 0, stream>>>(pA, pB, nAgg, alpha, params, (double)ND, dflag);
  k_fuse<<<NBLK, 256, 0, stream>>>(x, h, g, bgcn, bgat, gcn_nw, gcn_nb, gat_nw, gat_nb,
                                   params, pC, (long)ND, dflag);
  k_fin3<<<1, 256, 0, stream>>>(pC, params, (double)ND);
  k_final<<<(int)((ND + 255) / 256), 256, 0, stream>>>(h, out_nw, out_nb, params,
                                                       d_out, (long)ND, dflag);
}

// Round 6
// 572.409 us; speedup vs baseline: 5.5226x; 1.1836x over previous
//
#include <hip/hip_runtime.h>
#include <math.h>

#define DIM 128
#define HEADS 4
#define EPS 1e-5f
#define NBLK 1024

// ---------- dtype-flex helpers ----------
__device__ __forceinline__ float us2f(unsigned short u) {
  union { unsigned int i; float f; } c; c.i = ((unsigned int)u) << 16; return c.f;
}
__device__ __forceinline__ unsigned short f2us(float f) {
  union { float ff; unsigned int i; } c; c.ff = f;
  return (unsigned short)((c.i + 0x7FFFu + ((c.i >> 16) & 1u)) >> 16);
}
// fl32: 1 -> buffers hold float32, 0 -> bfloat16
__device__ __forceinline__ float ldf(const void* p, size_t i, int fl32) {
  return fl32 ? ((const float*)p)[i] : us2f(((const unsigned short*)p)[i]);
}
__device__ __forceinline__ float gelu_exact(float v) {
  return 0.5f * v * (1.0f + erff(v * 0.7071067811865475f));
}

// ---------- dtype detection (proven) ----------
__global__ void __launch_bounds__(256)
k_detect(const unsigned short* __restrict__ x, long n, int* __restrict__ dflag) {
  long lim = n < 8192 ? n : 8192;
  int bad = 0;
  for (long i = threadIdx.x; i < lim; i += 256) {
    float v = us2f(x[i]);
    float a = fabsf(v);
    if (!(a == 0.0f || (a > 1e-30f && a < 1e3f))) bad++;
  }
  __shared__ int sb[256];
  sb[threadIdx.x] = bad;
  __syncthreads();
  for (int off = 128; off > 0; off >>= 1) {
    if ((int)threadIdx.x < off) sb[threadIdx.x] += sb[threadIdx.x + off];
    __syncthreads();
  }
  if (threadIdx.x == 0) dflag[0] = (sb[0] > 32) ? 1 : 0;
}

// ---------- CSR construction ----------
__global__ void k_deg_cnt(const int* __restrict__ dst, const void* __restrict__ ew,
                          float* __restrict__ deg, int* __restrict__ cnt, int E,
                          const int* __restrict__ df) {
  const int fl32 = *df;
  int e = blockIdx.x * blockDim.x + threadIdx.x;
  if (e < E) {
    int d = dst[e];
    float w = ldf(ew, e, fl32);
    if (isfinite(w)) atomicAdd(&deg[d], w);
    atomicAdd(&cnt[d], 1);
  }
}

__global__ void k_dis(float* __restrict__ deg, int N) {
  int i = blockIdx.x * blockDim.x + threadIdx.x;
  if (i < N) {
    float d = deg[i];
    deg[i] = (d > 0.0f) ? rsqrtf(fmaxf(d, 1e-30f)) : 0.0f;
  }
}

__global__ void __launch_bounds__(256)
k_scan(const int* __restrict__ cnt, int* __restrict__ off, int N, int E) {
  __shared__ int part[256];
  int t = threadIdx.x;
  int chunk = (N + 255) / 256;
  int lo = t * chunk;
  int hi = lo + chunk; if (hi > N) hi = N;
  int s = 0;
  for (int i = lo; i < hi; ++i) s += cnt[i];
  part[t] = s;
  __syncthreads();
  if (t == 0) {
    int run = 0;
    for (int j = 0; j < 256; ++j) { int tmp = part[j]; part[j] = run; run += tmp; }
  }
  __syncthreads();
  int run = part[t];
  for (int i = lo; i < hi; ++i) { off[i] = run; run += cnt[i]; }
  if (t == 0) off[N] = E;
}

__global__ void k_scatter(const int* __restrict__ src, const int* __restrict__ dst,
                          const void* __restrict__ ew, const void* __restrict__ ea,
                          const float* __restrict__ dis, const int* __restrict__ off,
                          int* __restrict__ cursor, int* __restrict__ csr_src,
                          float* __restrict__ csr_nm, float* __restrict__ csr_ea,
                          int E, const int* __restrict__ df) {
  const int fl32 = *df;
  int e = blockIdx.x * blockDim.x + threadIdx.x;
  if (e >= E) return;
  int d = dst[e], s = src[e];
  int pos = off[d] + atomicAdd(&cursor[d], 1);
  csr_src[pos] = s;
  float nm = dis[s] * ldf(ew, e, fl32) * dis[d];
  if (!isfinite(nm)) nm = 0.0f;
  csr_nm[pos] = nm;
  float eav = ldf(ea, e, fl32);
  if (!isfinite(eav)) eav = 0.0f;
  csr_ea[pos] = eav;
}

// ---------- dual GEMM (unchanged) ----------
__global__ void __launch_bounds__(128)
k_gemm_dual(const void* __restrict__ x, const void* __restrict__ Wg,
            const void* __restrict__ Wl, const void* __restrict__ bl,
            unsigned short* __restrict__ xw, unsigned short* __restrict__ xl, int N,
            const int* __restrict__ df) {
  const int fl32 = *df;
  const int R = 8;
  __shared__ float xs[R][DIM];
  int c = threadIdx.x;
  int r0 = blockIdx.x * R;
  for (int r = 0; r < R; ++r) {
    int row = r0 + r;
    xs[r][c] = (row < N) ? ldf(x, (size_t)row * DIM + c, fl32) : 0.0f;
  }
  __syncthreads();
  float accg[R], accl[R];
  float blc = ldf(bl, c, fl32);
  #pragma unroll
  for (int r = 0; r < R; ++r) { accg[r] = 0.0f; accl[r] = blc; }
  for (int k = 0; k < DIM; ++k) {
    float wg = ldf(Wg, k * DIM + c, fl32);
    float wl = ldf(Wl, k * DIM + c, fl32);
    #pragma unroll
    for (int r = 0; r < R; ++r) {
      accg[r] = fmaf(xs[r][k], wg, accg[r]);
      accl[r] = fmaf(xs[r][k], wl, accl[r]);
    }
  }
  for (int r = 0; r < R; ++r) {
    int row = r0 + r;
    if (row < N) {
      float ag = accg[r], al = accl[r];
      if (!isfinite(ag)) ag = 0.0f;
      if (!isfinite(al)) al = 0.0f;
      xw[(size_t)row * DIM + c] = f2us(ag);
      xl[(size_t)row * DIM + c] = f2us(al);
    }
  }
}

// ---------- MEGA: single-pass online softmax + GCN/GAT agg + LN stats ----------
// one wave per node; lane owns channels (2*lane, 2*lane+1); head = lane/16
__global__ void __launch_bounds__(256)
k_mega(const int* __restrict__ off, const int* __restrict__ csr_src,
       const float* __restrict__ csr_nm, const float* __restrict__ csr_ea,
       const unsigned short* __restrict__ xw, const unsigned short* __restrict__ xl,
       const void* __restrict__ Wed, const void* __restrict__ att,
       const void* __restrict__ bgcn, const void* __restrict__ bgat,
       float* __restrict__ h, float* __restrict__ g,
       double* __restrict__ pA, double* __restrict__ pB, int N,
       const int* __restrict__ df) {
  const int fl32 = *df;
  int wid = threadIdx.x >> 6;
  int lane = threadIdx.x & 63;
  int node = blockIdx.x * 4 + wid;
  int c0 = lane * 2;
  float wd0 = ldf(Wed, c0, fl32), wd1 = ldf(Wed, c0 + 1, fl32);
  float at0 = ldf(att, c0, fl32), at1 = ldf(att, c0 + 1, fl32);
  double sA = 0.0, sA2 = 0.0, sB = 0.0, sB2 = 0.0;
  if (node < N) {
    int beg = off[node], end = off[node + 1];
    float xd0 = us2f(xl[(size_t)node * DIM + c0]);
    float xd1 = us2f(xl[(size_t)node * DIM + c0 + 1]);
    float mx = -INFINITY, den = 0.f;
    float ga0 = 0.f, ga1 = 0.f, hc0 = 0.f, hc1 = 0.f;
    // 1-deep software pipeline: prefetch csr triple + both gathers
    float eaP = 0.f, nmP = 0.f;
    ushort2 vP = make_ushort2(0, 0), uP = make_ushort2(0, 0);
    if (beg < end) {
      int s0 = csr_src[beg];
      eaP = csr_ea[beg];
      nmP = csr_nm[beg];
      vP = *(const ushort2*)(xl + (size_t)s0 * DIM + c0);
      uP = *(const ushort2*)(xw + (size_t)s0 * DIM + c0);
    }
    for (int i = beg; i < end; ++i) {
      float eav = eaP, nm = nmP;
      ushort2 v = vP, u = uP;
      int inext = i + 1;
      if (inext < end) {                      // issue next loads before compute
        int sN = csr_src[inext];
        eaP = csr_ea[inext];
        nmP = csr_nm[inext];
        vP = *(const ushort2*)(xl + (size_t)sN * DIM + c0);
        uP = *(const ushort2*)(xw + (size_t)sN * DIM + c0);
      }
      float vx = us2f(v.x), vy = us2f(v.y);
      float z0 = xd0 + vx + eav * wd0; z0 = (z0 > 0.f) ? z0 : 0.2f * z0;
      float z1 = xd1 + vy + eav * wd1; z1 = (z1 > 0.f) ? z1 : 0.2f * z1;
      float dot = z0 * at0 + z1 * at1;
      dot += __shfl_xor(dot, 1);
      dot += __shfl_xor(dot, 2);
      dot += __shfl_xor(dot, 4);
      dot += __shfl_xor(dot, 8);
      if (!isfinite(dot)) dot = 0.0f;
      // online softmax update (exp args always <= 0)
      float nmx = fmaxf(mx, dot);
      float corr = __expf(mx - nmx);          // first iter: exp(-inf)=0
      float w = __expf(dot - nmx);
      mx = nmx;
      den = fmaf(den, corr, w);
      ga0 = fmaf(ga0, corr, w * vx);
      ga1 = fmaf(ga1, corr, w * vy);
      hc0 = fmaf(nm, us2f(u.x), hc0);
      hc1 = fmaf(nm, us2f(u.y), hc1);
    }
    float inv = (end > beg) ? 1.0f / (den + 1e-16f) : 0.0f;
    ga0 *= inv; ga1 *= inv;
    if (!isfinite(ga0)) ga0 = 0.0f;
    if (!isfinite(ga1)) ga1 = 0.0f;
    if (!isfinite(hc0)) hc0 = 0.0f;
    if (!isfinite(hc1)) hc1 = 0.0f;
    *(float2*)(h + (size_t)node * DIM + c0) = make_float2(hc0, hc1);
    *(float2*)(g + (size_t)node * DIM + c0) = make_float2(ga0, ga1);
    float hA0 = hc0 + ldf(bgcn, c0, fl32), hA1 = hc1 + ldf(bgcn, c0 + 1, fl32);
    float gB0 = ga0 + ldf(bgat, c0, fl32), gB1 = ga1 + ldf(bgat, c0 + 1, fl32);
    sA  = (double)hA0 + (double)hA1;
    sA2 = (double)hA0 * hA0 + (double)hA1 * hA1;
    sB  = (double)gB0 + (double)gB1;
    sB2 = (double)gB0 * gB0 + (double)gB1 * gB1;
  }
  __shared__ double l1[256], l2[256], l3[256], l4[256];
  l1[threadIdx.x] = sA; l2[threadIdx.x] = sA2; l3[threadIdx.x] = sB; l4[threadIdx.x] = sB2;
  __syncthreads();
  for (int o = 128; o > 0; o >>= 1) {
    if ((int)threadIdx.x < o) {
      l1[threadIdx.x] += l1[threadIdx.x + o];
      l2[threadIdx.x] += l2[threadIdx.x + o];
      l3[threadIdx.x] += l3[threadIdx.x + o];
      l4[threadIdx.x] += l4[threadIdx.x + o];
    }
    __syncthreads();
  }
  if (threadIdx.x == 0) {
    pA[2 * blockIdx.x] = l1[0]; pA[2 * blockIdx.x + 1] = l2[0];
    pB[2 * blockIdx.x] = l3[0]; pB[2 * blockIdx.x + 1] = l4[0];
  }
}

// ---------- LN finalize / fuse / output ----------
__device__ __forceinline__ void ln_params(double S, double S2, double M, float* mu_out, float* sc_out) {
  double mu = S / M;
  double v = S2 / M - mu * mu;
  if (!(v > 0.0)) v = 0.0;
  float fmu = (float)mu;
  float sc = 1.0f / ((float)sqrt(v) + EPS);
  if (!isfinite(fmu)) fmu = 0.0f;
  if (!isfinite(sc)) sc = 0.0f;
  *mu_out = fmu; *sc_out = sc;
}

__global__ void __launch_bounds__(256)
k_fin12(const double* __restrict__ pA, const double* __restrict__ pB, int nblk,
        const void* __restrict__ alpha, float* __restrict__ params, double M,
        const int* __restrict__ df) {
  const int fl32 = *df;
  __shared__ double l1[256], l2[256], l3[256], l4[256];
  double a = 0, b = 0, c = 0, d = 0;
  for (int j = threadIdx.x; j < nblk; j += 256) {
    a += pA[2 * j]; b += pA[2 * j + 1];
    c += pB[2 * j]; d += pB[2 * j + 1];
  }
  l1[threadIdx.x] = a; l2[threadIdx.x] = b; l3[threadIdx.x] = c; l4[threadIdx.x] = d;
  __syncthreads();
  for (int off = 128; off > 0; off >>= 1) {
    if ((int)threadIdx.x < off) {
      l1[threadIdx.x] += l1[threadIdx.x + off];
      l2[threadIdx.x] += l2[threadIdx.x + off];
      l3[threadIdx.x] += l3[threadIdx.x + off];
      l4[threadIdx.x] += l4[threadIdx.x + off];
    }
    __syncthreads();
  }
  if (threadIdx.x == 0) {
    ln_params(l1[0], l2[0], M, &params[0], &params[1]);
    ln_params(l3[0], l4[0], M, &params[2], &params[3]);
    float a0 = ldf(alpha, 0, fl32), a1 = ldf(alpha, 1, fl32);
    if (!isfinite(a0)) a0 = 0.0f;
    if (!isfinite(a1)) a1 = 0.0f;
    float mx = fmaxf(a0, a1);
    float e0 = expf(a0 - mx), e1 = expf(a1 - mx);
    float inv = 1.0f / (e0 + e1);
    params[4] = e0 * inv;
    params[5] = e1 * inv;
  }
}

__global__ void __launch_bounds__(256)
k_fin3(const double* __restrict__ pC, float* __restrict__ params, double M) {
  __shared__ double l1[256], l2[256];
  double a = 0, b = 0;
  for (int j = threadIdx.x; j < NBLK; j += 256) { a += pC[2 * j]; b += pC[2 * j + 1]; }
  l1[threadIdx.x] = a; l2[threadIdx.x] = b;
  __syncthreads();
  for (int off = 128; off > 0; off >>= 1) {
    if ((int)threadIdx.x < off) {
      l1[threadIdx.x] += l1[threadIdx.x + off];
      l2[threadIdx.x] += l2[threadIdx.x + off];
    }
    __syncthreads();
  }
  if (threadIdx.x == 0) ln_params(l1[0], l2[0], M, &params[6], &params[7]);
}

__global__ void __launch_bounds__(256)
k_fuse(const void* __restrict__ x, float* h, const float* __restrict__ g,
       const void* __restrict__ b_gcn, const void* __restrict__ b_gat,
       const void* __restrict__ gcn_nw, const void* __restrict__ gcn_nb,
       const void* __restrict__ gat_nw, const void* __restrict__ gat_nb,
       const float* __restrict__ params, double* __restrict__ pC, long n,
       const int* __restrict__ df) {
  const int fl32 = *df;
  float mu1 = params[0], sc1 = params[1], mu2 = params[2], sc2 = params[3];
  float w0 = params[4], w1 = params[5];
  double s = 0.0, s2 = 0.0;
  long stride = (long)gridDim.x * blockDim.x;
  for (long i = (long)blockIdx.x * blockDim.x + threadIdx.x; i < n; i += stride) {
    size_t c = (size_t)(i & (DIM - 1));
    float xv = ldf(x, i, fl32);
    float hv = h[i] + ldf(b_gcn, c, fl32);
    float gv = g[i] + ldf(b_gat, c, fl32);
    float go = xv + gelu_exact((hv - mu1) * sc1 * ldf(gcn_nw, c, fl32) + ldf(gcn_nb, c, fl32));
    float ao = xv + gelu_exact((gv - mu2) * sc2 * ldf(gat_nw, c, fl32) + ldf(gat_nb, c, fl32));
    float f = w0 * go + w1 * ao;
    if (!isfinite(f)) f = 0.0f;
    h[i] = f;
    s += f; s2 += (double)f * f;
  }
  __shared__ double ls[256], ls2[256];
  ls[threadIdx.x] = s; ls2[threadIdx.x] = s2;
  __syncthreads();
  for (int off = 128; off > 0; off >>= 1) {
    if ((int)threadIdx.x < off) {
      ls[threadIdx.x] += ls[threadIdx.x + off];
      ls2[threadIdx.x] += ls2[threadIdx.x + off];
    }
    __syncthreads();
  }
  if (threadIdx.x == 0) { pC[2 * blockIdx.x] = ls[0]; pC[2 * blockIdx.x + 1] = ls2[0]; }
}

__global__ void k_final(const float* __restrict__ fused, const void* __restrict__ nw,
                        const void* __restrict__ nb, const float* __restrict__ params,
                        void* __restrict__ out, long n, const int* __restrict__ df) {
  const int fl32 = *df;
  long i = (long)blockIdx.x * blockDim.x + threadIdx.x;
  if (i >= n) return;
  size_t c = (size_t)(i & (DIM - 1));
  float mu = params[6], sc = params[7];
  float r = gelu_exact((fused[i] - mu) * sc * ldf(nw, c, fl32) + ldf(nb, c, fl32));
  if (!isfinite(r)) r = 0.0f;
  if (fl32) ((float*)out)[i] = r;
  else      ((unsigned short*)out)[i] = f2us(r);
}

extern "C" void kernel_launch(void* const* d_in, const int* in_sizes, int n_in,
                              void* d_out, int out_size, void* d_ws, size_t ws_size,
                              hipStream_t stream) {
  const void* x    = d_in[0];
  const int*  ei   = (const int*)d_in[1];
  const void* ew   = d_in[2];
  const void* ea   = d_in[3];
  const void* Wg   = d_in[4];
  const void* bgcn = d_in[5];
  const void* Wl   = d_in[6];
  const void* bl   = d_in[7];
  const void* Wed  = d_in[8];
  const void* att  = d_in[9];
  const void* bgat = d_in[10];
  const void* gcn_nw = d_in[11];
  const void* gcn_nb = d_in[12];
  const void* gat_nw = d_in[13];
  const void* gat_nb = d_in[14];
  const void* out_nw = d_in[15];
  const void* out_nb = d_in[16];
  const void* alpha  = d_in[17];

  const int N = in_sizes[0] / DIM;
  const int E = in_sizes[2];
  const int* src  = ei;
  const int* dstp = ei + E;
  const size_t ND = (size_t)N * DIM;
  const int nAgg = (N + 3) / 4;  // mega grid (4 waves/block)

  char* ws = (char*)d_ws;
  size_t o = 0;
  auto alloc = [&](size_t bytes) { size_t r = o; o += (bytes + 255) & ~(size_t)255; return r; };
  size_t o_deg    = alloc((size_t)N * 4);
  size_t o_cnt    = alloc((size_t)N * 4);
  size_t o_cursor = alloc((size_t)N * 4);
  size_t zero_end = o;                         // [0, zero_end) memset to 0
  size_t o_off    = alloc((size_t)(N + 1) * 4);
  size_t o_h      = alloc(ND * 4);
  size_t o_g      = alloc(ND * 4);
  size_t o_xw     = alloc(ND * 2);
  size_t o_xl     = alloc(ND * 2);
  size_t o_csrc   = alloc((size_t)E * 4);
  size_t o_cnm    = alloc((size_t)E * 4);
  size_t o_cea    = alloc((size_t)E * 4);
  size_t o_par    = alloc(8 * 4);
  size_t o_pA     = alloc((size_t)nAgg * 2 * 8);
  size_t o_pB     = alloc((size_t)nAgg * 2 * 8);
  size_t o_pC     = alloc((size_t)NBLK * 2 * 8);
  size_t o_flag   = alloc(4);
  (void)ws_size; (void)n_in; (void)out_size;

  float* deg     = (float*)(ws + o_deg);
  int*   cnt     = (int*)(ws + o_cnt);
  int*   cursor  = (int*)(ws + o_cursor);
  int*   off     = (int*)(ws + o_off);
  float* h       = (float*)(ws + o_h);
  float* g       = (float*)(ws + o_g);
  unsigned short* xw = (unsigned short*)(ws + o_xw);
  unsigned short* xl = (unsigned short*)(ws + o_xl);
  int*   csr_src = (int*)(ws + o_csrc);
  float* csr_nm  = (float*)(ws + o_cnm);
  float* csr_ea  = (float*)(ws + o_cea);
  float* params  = (float*)(ws + o_par);
  double* pA     = (double*)(ws + o_pA);
  double* pB     = (double*)(ws + o_pB);
  double* pC     = (double*)(ws + o_pC);
  int* dflag     = (int*)(ws + o_flag);

  hipMemsetAsync(ws, 0, zero_end, stream);
  k_detect<<<1, 256, 0, stream>>>((const unsigned short*)x, (long)ND, dflag);

  int ebk = (E + 255) / 256;
  k_deg_cnt<<<ebk, 256, 0, stream>>>(dstp, ew, deg, cnt, E, dflag);
  k_dis<<<(N + 255) / 256, 256, 0, stream>>>(deg, N);
  k_scan<<<1, 256, 0, stream>>>(cnt, off, N, E);
  k_scatter<<<ebk, 256, 0, stream>>>(src, dstp, ew, ea, deg, off, cursor,
                                     csr_src, csr_nm, csr_ea, E, dflag);

  k_gemm_dual<<<(N + 7) / 8, 128, 0, stream>>>(x, Wg, Wl, bl, xw, xl, N, dflag);

  k_mega<<<nAgg, 256, 0, stream>>>(off, csr_src, csr_nm, csr_ea, xw, xl,
                                   Wed, att, bgcn, bgat, h, g, pA, pB, N, dflag);

  k_fin12<<<1, 256, 0, stream>>>(pA, pB, nAgg, alpha, params, (double)ND, dflag);
  k_fuse<<<NBLK, 256, 0, stream>>>(x, h, g, bgcn, bgat, gcn_nw, gcn_nb, gat_nw, gat_nb,
                                   params, pC, (long)ND, dflag);
  k_fin3<<<1, 256, 0, stream>>>(pC, params, (double)ND);
  k_final<<<(int)((ND + 255) / 256), 256, 0, stream>>>(h, out_nw, out_nb, params,
                                                       d_out, (long)ND, dflag);
}